// Round 21
// baseline (446.451 us; speedup 1.0000x reference)
//
#include <hip/hip_runtime.h>
#include <stdint.h>

typedef unsigned short u16;
typedef __attribute__((ext_vector_type(4))) float f32x4;
typedef __attribute__((ext_vector_type(8))) __bf16 bf16x8;
typedef __attribute__((ext_vector_type(4))) u16 u16x4;
typedef __attribute__((ext_vector_type(8))) u16 u16x8;

#define T_SEQ 2048
#define NB 4
#define NH 16
#define NKV 4
#define HDIM 128
#define PSTR 72

__device__ __forceinline__ u16 f2bf(float f) {
  __bf16 h = (__bf16)f;
  return __builtin_bit_cast(u16, h);
}
__device__ __forceinline__ float bf2f(u16 u) {
  union { uint32_t u; float f; } v; v.u = ((uint32_t)u) << 16;
  return v.f;
}
__device__ __forceinline__ void gload16(const void* g, void* l) {
  __builtin_amdgcn_global_load_lds((const __attribute__((address_space(1))) void*)g,
                                   (__attribute__((address_space(3))) void*)l, 16, 0, 0);
}
__device__ __forceinline__ f32x4 mfma16(bf16x8 a, bf16x8 b, f32x4 c) {
  return __builtin_amdgcn_mfma_f32_16x16x32_bf16(a, b, c, 0, 0, 0);
}

// ------------- fused fp32 -> bf16 convert for all 5 inputs (1 launch) -------------
__global__ __launch_bounds__(256) void cvt_all(const float* __restrict__ x,
                                               const float* __restrict__ wq,
                                               const float* __restrict__ wk,
                                               const float* __restrict__ wv,
                                               const float* __restrict__ wp,
                                               u16* __restrict__ xo, u16* __restrict__ wqo,
                                               u16* __restrict__ wko, u16* __restrict__ wvo,
                                               u16* __restrict__ wpo) {
  const int C_X = 16777216 / 4, C_WQ = 4194304 / 4, C_WKV = 1048576 / 4;
  const int B1 = C_X, B2 = B1 + C_WQ, B3 = B2 + C_WKV, B4 = B3 + C_WKV;
  const int total = B4 + C_WQ;
  int idx = blockIdx.x * 256 + threadIdx.x;
  int stride = gridDim.x * 256;
  for (int c = idx; c < total; c += stride) {
    const float* src;
    u16* dst;
    int off;
    if (c < B1)      { src = x;  dst = xo;  off = c; }
    else if (c < B2) { src = wq; dst = wqo; off = c - B1; }
    else if (c < B3) { src = wk; dst = wko; off = c - B2; }
    else if (c < B4) { src = wv; dst = wvo; off = c - B3; }
    else             { src = wp; dst = wpo; off = c - B4; }
    f32x4 v = *(const f32x4*)(src + (size_t)off * 4);
    u16x4 o;
    o[0] = f2bf(v[0]); o[1] = f2bf(v[1]); o[2] = f2bf(v[2]); o[3] = f2bf(v[3]);
    *(u16x4*)(dst + (size_t)off * 4) = o;
  }
}

// --- 128x128 bf16 GEMM: BK=32, 3-buffer LDS, counted vmcnt(4), raw barrier ---
// Bt is (N,K) row-major. MODE 1: fp32 C. MODE 2: kv scatter (N=1024, n<512 -> k).
template <int MODE>
__global__ __launch_bounds__(256) void gemm128p3(const u16* __restrict__ A,
                                                 const u16* __restrict__ Bt,
                                                 u16* __restrict__ k_o, u16* __restrict__ v_o,
                                                 float* __restrict__ f_o,
                                                 int K, int nx, int cpx) {
  __shared__ __align__(16) u16 As3[3 * 128 * 32];
  __shared__ __align__(16) u16 Bs3[3 * 128 * 32];
  const int tid = threadIdx.x;
  const int l = tid & 63, w = tid >> 6;
  const int l15 = l & 15, g16 = l >> 4;
  const int wr = w >> 1, wc = w & 1;

  const int oid = blockIdx.x + nx * blockIdx.y;
  const int wid = (oid & 7) * cpx + (oid >> 3);
  const int m0 = (wid / nx) * 128, n0 = (wid % nx) * 128;

  f32x4 acc[4][4] = {};

  const int row0 = tid >> 2, row1 = 64 + (tid >> 2), cc = tid & 3;
  const int sc0 = cc ^ ((row0 >> 1) & 3), sc1 = cc ^ ((row1 >> 1) & 3);
  const u16* pA0 = A + (size_t)(m0 + row0) * K + sc0 * 8;
  const u16* pA1 = A + (size_t)(m0 + row1) * K + sc1 * 8;
  const u16* pB0 = Bt + (size_t)(n0 + row0) * K + sc0 * 8;
  const u16* pB1 = Bt + (size_t)(n0 + row1) * K + sc1 * 8;

#define STAGE(buf)                                                   \
  {                                                                  \
    char* ab = (char*)As3 + (buf) * 8192 + w * 1024;                 \
    char* bb = (char*)Bs3 + (buf) * 8192 + w * 1024;                 \
    gload16(pA0, ab);                                                \
    gload16(pA1, ab + 4096);                                         \
    gload16(pB0, bb);                                                \
    gload16(pB1, bb + 4096);                                         \
    pA0 += 32; pA1 += 32; pB0 += 32; pB1 += 32;                      \
  }

#define COMPUTE(buf)                                                 \
  {                                                                  \
    const u16* AsB = As3 + (buf) * 4096;                             \
    const u16* BsB = Bs3 + (buf) * 4096;                             \
    bf16x8 af[4], bfr[4];                                            \
    _Pragma("unroll")                                                \
    for (int mt = 0; mt < 4; ++mt) {                                 \
      int arow = wr * 64 + mt * 16 + l15;                            \
      af[mt] = *(const bf16x8*)&AsB[arow * 32 +                      \
                                    ((g16 ^ ((arow >> 1) & 3)) * 8)];\
    }                                                                \
    _Pragma("unroll")                                                \
    for (int nt = 0; nt < 4; ++nt) {                                 \
      int brow = wc * 64 + nt * 16 + l15;                            \
      bfr[nt] = *(const bf16x8*)&BsB[brow * 32 +                     \
                                     ((g16 ^ ((brow >> 1) & 3)) * 8)];\
    }                                                                \
    __builtin_amdgcn_s_setprio(1);                                   \
    _Pragma("unroll")                                                \
    for (int mt = 0; mt < 4; ++mt)                                   \
      _Pragma("unroll")                                              \
      for (int nt = 0; nt < 4; ++nt)                                 \
        acc[mt][nt] = mfma16(af[mt], bfr[nt], acc[mt][nt]);          \
    __builtin_amdgcn_s_setprio(0);                                   \
  }

  const int ntiles = K >> 5;
  STAGE(0);
  STAGE(1);
  asm volatile("s_waitcnt vmcnt(4)" ::: "memory");
  __builtin_amdgcn_s_barrier();

  int cur = 0, nxt = 2;
  for (int t = 0; t < ntiles; ++t) {
    const bool more2 = (t + 2 < ntiles);
    if (more2) STAGE(nxt);
    COMPUTE(cur);
    if (t + 1 < ntiles) {
      if (more2) {
        asm volatile("s_waitcnt vmcnt(4)" ::: "memory");
      } else {
        asm volatile("s_waitcnt vmcnt(0)" ::: "memory");
      }
      __builtin_amdgcn_s_barrier();
    }
    cur = (cur == 2) ? 0 : cur + 1;
    nxt = (nxt == 2) ? 0 : nxt + 1;
  }
#undef STAGE
#undef COMPUTE

#pragma unroll
  for (int mt = 0; mt < 4; ++mt) {
#pragma unroll
    for (int r = 0; r < 4; ++r) {
      int row = m0 + wr * 64 + mt * 16 + g16 * 4 + r;
#pragma unroll
      for (int nt = 0; nt < 4; ++nt) {
        int n = n0 + wc * 64 + nt * 16 + l15;
        float val = acc[mt][nt][r];
        if (MODE == 1) {
          f_o[(size_t)row * 2048 + n] = val;
        } else {  // MODE 2: kv scatter, n in [0,1024)
          int b = row >> 11, t = row & (T_SEQ - 1);
          u16 bv = f2bf(val);
          if (n < 512) {
            int h = n >> 7, d = n & 127;
            k_o[((size_t)(b * NKV + h) * T_SEQ + t) * HDIM + d] = bv;
          } else {
            int n2 = n - 512; int h = n2 >> 7, d = n2 & 127;
            v_o[((size_t)(b * NKV + h) * T_SEQ + t) * HDIM + d] = bv;
          }
        }
      }
    }
  }
}

// ---- 256x256 bf16 GEMM: 512 thr (8 waves 2x4), per-wave 128x64, BK=64 ----
// Grid MUST be exactly 256 blocks (1 round, 1 block/CU). MODE 0: q scatter
// (N=2048). MODE 1: fp32 C.
template <int MODE>
__global__ __launch_bounds__(512, 2) void gemm256(const u16* __restrict__ A,
                                                  const u16* __restrict__ Bt,
                                                  u16* __restrict__ q_o,
                                                  float* __restrict__ f_o,
                                                  int K, int ntn, int cpx) {
  __shared__ __align__(16) u16 As[2][256 * 64];
  __shared__ __align__(16) u16 Bs[2][256 * 64];
  const int tid = threadIdx.x;
  const int l = tid & 63, w = tid >> 6;
  const int l16 = l & 15, g16 = l >> 4;
  const int wr = w >> 2, wc = w & 3;

  const int oid = blockIdx.x;
  const int wid = (oid & 7) * cpx + (oid >> 3);
  const int m0 = (wid / ntn) * 256, n0 = (wid % ntn) * 256;

  f32x4 acc[8][4] = {};

  const int srow = tid >> 3, scc = tid & 7;
  const u16* pA[4];
  const u16* pB[4];
#pragma unroll
  for (int j = 0; j < 4; ++j) {
    int row = j * 64 + srow;
    int cc = scc ^ (row & 7);
    pA[j] = A + (size_t)(m0 + row) * K + cc * 8;
    pB[j] = Bt + (size_t)(n0 + row) * K + cc * 8;
  }

#define STAGE(buf)                                              \
  {                                                             \
    char* ab = (char*)As[buf] + w * 1024;                       \
    char* bb = (char*)Bs[buf] + w * 1024;                       \
    _Pragma("unroll")                                           \
    for (int j = 0; j < 4; ++j) {                               \
      gload16(pA[j], ab + j * 8192);                            \
      pA[j] += 64;                                              \
    }                                                           \
    _Pragma("unroll")                                           \
    for (int j = 0; j < 4; ++j) {                               \
      gload16(pB[j], bb + j * 8192);                            \
      pB[j] += 64;                                              \
    }                                                           \
  }

  const int ntk = K >> 6;
  STAGE(0);
  __syncthreads();

  for (int t = 0; t < ntk; ++t) {
    const int buf = t & 1;
    if (t + 1 < ntk) STAGE(buf ^ 1);
#pragma unroll
    for (int ks = 0; ks < 2; ++ks) {
      bf16x8 bfr[4];
#pragma unroll
      for (int nf = 0; nf < 4; ++nf) {
        int brow = wc * 64 + nf * 16 + l16;
        int slot = (ks * 4 + g16) ^ (brow & 7);
        bfr[nf] = *(const bf16x8*)&Bs[buf][brow * 64 + slot * 8];
      }
#pragma unroll
      for (int rh = 0; rh < 2; ++rh) {
        bf16x8 af[4];
#pragma unroll
        for (int f = 0; f < 4; ++f) {
          int arow = wr * 128 + rh * 64 + f * 16 + l16;
          int slot = (ks * 4 + g16) ^ (arow & 7);
          af[f] = *(const bf16x8*)&As[buf][arow * 64 + slot * 8];
        }
        __builtin_amdgcn_s_setprio(1);
#pragma unroll
        for (int f = 0; f < 4; ++f)
#pragma unroll
          for (int nf = 0; nf < 4; ++nf)
            acc[rh * 4 + f][nf] = mfma16(af[f], bfr[nf], acc[rh * 4 + f][nf]);
        __builtin_amdgcn_s_setprio(0);
      }
    }
    __syncthreads();
  }
#undef STAGE

#pragma unroll
  for (int rf = 0; rf < 8; ++rf) {
#pragma unroll
    for (int rr = 0; rr < 4; ++rr) {
      int row = m0 + wr * 128 + rf * 16 + g16 * 4 + rr;
#pragma unroll
      for (int nf = 0; nf < 4; ++nf) {
        int n = n0 + wc * 64 + nf * 16 + l16;
        float val = acc[rf][nf][rr];
        if (MODE == 1) {
          f_o[(size_t)row * 2048 + n] = val;
        } else {  // MODE 0: q scatter (n < 2048 always)
          int b = row >> 11, t = row & (T_SEQ - 1);
          int h = n >> 7, d = n & 127;
          q_o[((size_t)(b * NH + h) * T_SEQ + t) * HDIM + d] = f2bf(val);
        }
      }
    }
  }
}

// ------ merged post-processing: q-rmsrope | k-rmsrope | vtrans (1 launch) ------
// blocks [0,32768): q rows x4; [32768,40960): k rows x4; [40960,41984): vtrans.
__global__ __launch_bounds__(256) void postproc(u16* __restrict__ qbuf,
                                                u16* __restrict__ kbuf,
                                                const u16* __restrict__ vbuf,
                                                u16* __restrict__ vtbuf,
                                                const float* __restrict__ gains) {
  const int bid = blockIdx.x;
  if (bid < 40960) {
    const bool isq = (bid < 32768);
    u16* buf = isq ? qbuf : kbuf;
    const int base = isq ? bid : (bid - 32768);
    const int w = threadIdx.x >> 6, l = threadIdx.x & 63;
    const int rid = base * 4 + w;
    const int t = rid & (T_SEQ - 1);
    const int h = (rid >> 11) % (isq ? NH : NKV);
    u16* p = buf + (size_t)rid * HDIM;
    float x1 = bf2f(p[l]), x2 = bf2f(p[l + 64]);
    float ss = x1 * x1 + x2 * x2;
#pragma unroll
    for (int m = 32; m; m >>= 1) ss += __shfl_xor(ss, m, 64);
    float rn = rsqrtf(ss * (1.0f / 128.0f) + 1.1920928955078125e-7f);
    float g = isq ? gains[h] * (1.4426950408889634f / 11.313708498984761f) : 1.0f;
    float sc = rn * g;
    float inv = exp2f(-(float)l * (13.287712379549449f / 64.0f));
    float ang = (float)t * inv;
    float s, c;
    __sincosf(ang, &s, &c);
    float o1 = (x1 * c + x2 * s) * sc;
    float o2 = (x2 * c - x1 * s) * sc;
    p[l] = f2bf(o1);
    p[l + 64] = f2bf(o2);
  } else {
    __shared__ u16 tileT[64][PSTR];
    const int tidx = bid - 40960;
    const int t0 = (tidx & 31) * 64, d0 = ((tidx >> 5) & 1) * 64, bg = tidx >> 6;
    const int tid = threadIdx.x;
    const int row = tid >> 2, c0 = (tid & 3) * 16;
    const u16* src = vbuf + ((size_t)bg * T_SEQ + t0 + row) * HDIM + d0 + c0;
    u16x8 a = *(const u16x8*)src;
    u16x8 bb = *(const u16x8*)(src + 8);
#pragma unroll
    for (int j = 0; j < 8; ++j) {
      tileT[c0 + j][row] = a[j];
      tileT[c0 + 8 + j][row] = bb[j];
    }
    __syncthreads();
    u16* dst = vtbuf + ((size_t)bg * HDIM + d0 + row) * T_SEQ + t0 + c0;
    *(u16x8*)dst = *(const u16x8*)&tileT[row][c0];
    *(u16x8*)(dst + 8) = *(const u16x8*)&tileT[row][c0 + 8];
  }
}

// ---- flash GQA causal attention v11: fused dual q-tile (qt=p and qt=15-p) ----
// Each KV tile staged ONCE; on the shared prefix both q-sets compute -> two
// independent MFMA/VALU chains per tile (cross-chain ILP). 512 thr, 8 waves x
// 16 q-rows per set. Ps XOR-swizzled, per-wave private (sequential A then B).
__global__ __launch_bounds__(512, 4) void attn_fwd11(const u16* __restrict__ qb,
                                                     const u16* __restrict__ kb,
                                                     const u16* __restrict__ vtb,
                                                     u16* __restrict__ yb,
                                                     const float* __restrict__ gains) {
  __shared__ __align__(16) u16 Ks[64 * 128];    // [key][d], chunk XOR (row&7)
  __shared__ __align__(16) u16 Vs[128 * 64];    // [d][key], chunk XOR (row&7)
  __shared__ __align__(16) u16 Ps[8][16 * 64];  // per-wave P, XOR-swizzled

  const int tid = threadIdx.x, l = tid & 63, w = tid >> 6;  // w: 0..7
  const int l16 = l & 15, g16 = l >> 4;
  const int pswz = (l16 & 7) * 8;   // u16-index XOR for Ps

  const int oid = blockIdx.x + 8 * blockIdx.y;
  const int wid = (oid & 7) * 64 + (oid >> 3);
  const int pair = wid & 7, bh = wid >> 3;
  const int b = bh >> 4, h = bh & 15, gr = h >> 2;

  const float Mh = 16.33f * fabsf(gains[h]) + 0.5f;
  const u16* kbase = kb + (size_t)(b * NKV + gr) * T_SEQ * HDIM;
  const u16* vtbase = vtb + (size_t)(b * NKV + gr) * HDIM * T_SEQ;

  bf16x8 ones;
#pragma unroll
  for (int j = 0; j < 8; ++j) ones[j] = (__bf16)1.0f;

  // persistent staging source pointers (computed once; advance per tile)
  const int krow0 = tid >> 4, kc0 = tid & 15;
  const int krow1 = 32 + (tid >> 4);
  const u16* kp0 = kbase + (size_t)krow0 * HDIM + (kc0 ^ (krow0 & 7)) * 8;
  const u16* kp1 = kbase + (size_t)krow1 * HDIM + (kc0 ^ (krow1 & 7)) * 8;
  const int vrow0 = tid >> 3, vc0 = tid & 7;
  const int vrow1 = 64 + (tid >> 3);
  const u16* vp0 = vtbase + (size_t)vrow0 * T_SEQ + (vc0 ^ (vrow0 & 7)) * 8;
  const u16* vp1 = vtbase + (size_t)vrow1 * T_SEQ + (vc0 ^ (vrow1 & 7)) * 8;
  char* kd0 = (char*)Ks + (w * 64) * 16;
  char* kd1 = (char*)Ks + (512 + w * 64) * 16;
  char* vd0 = (char*)Vs + (w * 64) * 16;
  char* vd1 = (char*)Vs + (512 + w * 64) * 16;

  // two q-sets: A = qt=pair (small range), B = qt=15-pair (large range)
  const int q0a = pair * 128 + w * 16;
  const int q0b = (15 - pair) * 128 + w * 16;
  const int qhia = q0a + 15;

  bf16x8 qfa[4], qfb[4];
  {
    const u16* qba = qb + ((size_t)bh * T_SEQ + q0a) * HDIM;
    const u16* qbb = qb + ((size_t)bh * T_SEQ + q0b) * HDIM;
#pragma unroll
    for (int s = 0; s < 4; ++s) {
      qfa[s] = *(const bf16x8*)(qba + (size_t)l16 * HDIM + s * 32 + g16 * 8);
      qfb[s] = *(const bf16x8*)(qbb + (size_t)l16 * HDIM + s * 32 + g16 * 8);
    }
  }

  f32x4 oacca[8] = {}, oaccb[8] = {};
  f32x4 ddena = {}, ddenb = {};
  const int ntb = 2 * (15 - pair) + 2;   // B's range = loop bound (A's subset)

#define ATT_SET(KT, QF, Q0, OACC, DDEN)                                    \
  {                                                                        \
    f32x4 sacc[4] = {};                                                    \
    __builtin_amdgcn_s_setprio(1);                                         \
    _Pragma("unroll")                                                      \
    for (int mt = 0; mt < 4; ++mt) {                                       \
      int key = mt * 16 + l16;                                             \
      _Pragma("unroll")                                                    \
      for (int s = 0; s < 4; ++s) {                                        \
        bf16x8 kf = *(const bf16x8*)&Ks[key * 128 +                        \
                                    (((s * 4 + g16) ^ (key & 7)) * 8)];    \
        sacc[mt] = mfma16(kf, QF[s], sacc[mt]);                            \
      }                                                                    \
    }                                                                      \
    __builtin_amdgcn_s_setprio(0);                                         \
    if ((KT) * 64 + 63 > (Q0)) {                                           \
      _Pragma("unroll")                                                    \
      for (int mt = 0; mt < 4; ++mt) {                                     \
        int keyb = (KT) * 64 + mt * 16 + g16 * 4;                          \
        u16x4 p4;                                                          \
        _Pragma("unroll")                                                  \
        for (int r = 0; r < 4; ++r) {                                      \
          float pv = exp2f(sacc[mt][r] - Mh);                              \
          if (keyb + r > (Q0) + l16) pv = 0.f;                             \
          p4[r] = f2bf(pv);                                                \
        }                                                                  \
        *(u16x4*)&Ps[w][l16 * 64 + ((mt * 16 + g16 * 4) ^ pswz)] = p4;     \
      }                                                                    \
    } else {                                                               \
      _Pragma("unroll")                                                    \
      for (int mt = 0; mt < 4; ++mt) {                                     \
        u16x4 p4;                                                          \
        _Pragma("unroll")                                                  \
        for (int r = 0; r < 4; ++r)                                        \
          p4[r] = f2bf(exp2f(sacc[mt][r] - Mh));                           \
        *(u16x4*)&Ps[w][l16 * 64 + ((mt * 16 + g16 * 4) ^ pswz)] = p4;     \
      }                                                                    \
    }                                                                      \
    __builtin_amdgcn_s_setprio(1);                                         \
    _Pragma("unroll")                                                      \
    for (int ks = 0; ks < 2; ++ks) {                                       \
      bf16x8 pa = *(const bf16x8*)&Ps[w][l16 * 64 +                        \
                                         ((ks * 32 + g16 * 8) ^ pswz)];    \
      DDEN = mfma16(pa, ones, DDEN);                                       \
      _Pragma("unroll")                                                    \
      for (int dt = 0; dt < 8; ++dt) {                                     \
        int d = dt * 16 + l16;                                             \
        bf16x8 vv = *(const bf16x8*)&Vs[d * 64 +                           \
                                    (((ks * 4 + g16) ^ (d & 7)) * 8)];     \
        OACC[dt] = mfma16(pa, vv, OACC[dt]);                               \
      }                                                                    \
    }                                                                      \
    __builtin_amdgcn_s_setprio(0);                                         \
  }

  for (int kt = 0; kt < ntb; ++kt) {
    gload16(kp0, kd0);
    gload16(kp1, kd1);
    gload16(vp0, vd0);
    gload16(vp1, vd1);
    kp0 += 64 * HDIM; kp1 += 64 * HDIM;
    vp0 += 64; vp1 += 64;
    __syncthreads();

    if (kt * 64 <= qhia) ATT_SET(kt, qfa, q0a, oacca, ddena);  // prefix only
    ATT_SET(kt, qfb, q0b, oaccb, ddenb);                       // always active
    __syncthreads();
  }
#undef ATT_SET

  // outputs for both sets
  float rdena[4], rdenb[4];
#pragma unroll
  for (int r = 0; r < 4; ++r) {
    rdena[r] = 1.f / ddena[r];
    rdenb[r] = 1.f / ddenb[r];
  }
#pragma unroll
  for (int dt = 0; dt < 8; ++dt)
#pragma unroll
    for (int r = 0; r < 4; ++r) {
      int d = dt * 16 + l16;
      int ta = q0a + g16 * 4 + r;
      int tb = q0b + g16 * 4 + r;
      yb[(((size_t)b * T_SEQ + ta) * NH + h) * HDIM + d] = f2bf(oacca[dt][r] * rdena[r]);
      yb[(((size_t)b * T_SEQ + tb) * NH + h) * HDIM + d] = f2bf(oaccb[dt][r] * rdenb[r]);
    }
}

extern "C" void kernel_launch(void* const* d_in, const int* in_sizes, int n_in,
                              void* d_out, int out_size, void* d_ws, size_t ws_size,
                              hipStream_t stream) {
  const float* x = (const float*)d_in[0];
  const float* Wq = (const float*)d_in[1];
  const float* Wk = (const float*)d_in[2];
  const float* Wv = (const float*)d_in[3];
  const float* Wproj = (const float*)d_in[4];
  const float* qg = (const float*)d_in[5];
  float* out = (float*)d_out;

  u16* xbf = (u16*)d_ws;                                   // 8192*2048
  u16* Wqkv = xbf + (size_t)8192 * 2048;                   // 3072*2048 (dead after gemms)
  u16* Wpj = Wqkv + (size_t)3072 * 2048;                   // 2048*2048
  u16* qbuf = Wpj + (size_t)2048 * 2048;                   // 8192*2048
  u16* kbuf = qbuf + (size_t)8192 * 2048;                  // 2048*2048
  u16* vbuf = kbuf + (size_t)2048 * 2048;                  // 2048*2048
  u16* ybuf = xbf;        // alias: x dead after gemms
  u16* vtbuf = Wqkv;      // alias: Wqkv dead after gemms

  cvt_all<<<2048, 256, 0, stream>>>(x, Wq, Wk, Wv, Wproj,
                                    xbf, Wqkv, Wqkv + (size_t)2048 * 2048,
                                    Wqkv + (size_t)2560 * 2048, Wpj);

  // q projection: M=8192 N=2048 -> 32x8 = 256 blocks = exactly 1 round
  gemm256<0><<<256, 512, 0, stream>>>(xbf, Wqkv, qbuf, nullptr, 2048, 8, 32);

  // k+v projection: M=8192 N=1024 -> 8x64 = 512 blocks, 2/CU co-resident
  gemm128p3<2><<<dim3(8, 64), 256, 0, stream>>>(xbf, Wqkv + (size_t)2048 * 2048,
                                                kbuf, vbuf, nullptr, 2048, 8, 64);

  // merged q-rmsrope + k-rmsrope + vtrans (1 launch, 41984 blocks)
  postproc<<<41984, 256, 0, stream>>>(qbuf, kbuf, vbuf, vtbuf, qg);

  attn_fwd11<<<dim3(8, 64), 512, 0, stream>>>(qbuf, kbuf, vtbuf, ybuf, qg);

  gemm256<1><<<256, 512, 0, stream>>>(ybuf, Wpj, nullptr, out, 2048, 8, 32);
}

// Round 22
// 331.649 us; speedup vs baseline: 1.3462x; 1.3462x over previous
//
#include <hip/hip_runtime.h>
#include <stdint.h>

typedef unsigned short u16;
typedef __attribute__((ext_vector_type(4))) float f32x4;
typedef __attribute__((ext_vector_type(8))) __bf16 bf16x8;
typedef __attribute__((ext_vector_type(4))) u16 u16x4;
typedef __attribute__((ext_vector_type(8))) u16 u16x8;

#define T_SEQ 2048
#define NB 4
#define NH 16
#define NKV 4
#define HDIM 128
#define PSTR 72

__device__ __forceinline__ u16 f2bf(float f) {
  __bf16 h = (__bf16)f;
  return __builtin_bit_cast(u16, h);
}
__device__ __forceinline__ float bf2f(u16 u) {
  union { uint32_t u; float f; } v; v.u = ((uint32_t)u) << 16;
  return v.f;
}
__device__ __forceinline__ void gload16(const void* g, void* l) {
  __builtin_amdgcn_global_load_lds((const __attribute__((address_space(1))) void*)g,
                                   (__attribute__((address_space(3))) void*)l, 16, 0, 0);
}
__device__ __forceinline__ f32x4 mfma16(bf16x8 a, bf16x8 b, f32x4 c) {
  return __builtin_amdgcn_mfma_f32_16x16x32_bf16(a, b, c, 0, 0, 0);
}

// ------------- fused fp32 -> bf16 convert for all 5 inputs (1 launch) -------------
__global__ __launch_bounds__(256) void cvt_all(const float* __restrict__ x,
                                               const float* __restrict__ wq,
                                               const float* __restrict__ wk,
                                               const float* __restrict__ wv,
                                               const float* __restrict__ wp,
                                               u16* __restrict__ xo, u16* __restrict__ wqo,
                                               u16* __restrict__ wko, u16* __restrict__ wvo,
                                               u16* __restrict__ wpo) {
  const int C_X = 16777216 / 4, C_WQ = 4194304 / 4, C_WKV = 1048576 / 4;
  const int B1 = C_X, B2 = B1 + C_WQ, B3 = B2 + C_WKV, B4 = B3 + C_WKV;
  const int total = B4 + C_WQ;
  int idx = blockIdx.x * 256 + threadIdx.x;
  int stride = gridDim.x * 256;
  for (int c = idx; c < total; c += stride) {
    const float* src;
    u16* dst;
    int off;
    if (c < B1)      { src = x;  dst = xo;  off = c; }
    else if (c < B2) { src = wq; dst = wqo; off = c - B1; }
    else if (c < B3) { src = wk; dst = wko; off = c - B2; }
    else if (c < B4) { src = wv; dst = wvo; off = c - B3; }
    else             { src = wp; dst = wpo; off = c - B4; }
    f32x4 v = *(const f32x4*)(src + (size_t)off * 4);
    u16x4 o;
    o[0] = f2bf(v[0]); o[1] = f2bf(v[1]); o[2] = f2bf(v[2]); o[3] = f2bf(v[3]);
    *(u16x4*)(dst + (size_t)off * 4) = o;
  }
}

// --- 128x128 bf16 GEMM: BK=32, 3-buffer LDS, counted vmcnt(4), raw barrier ---
// Bt is (N,K) row-major. MODE 1: fp32 C. MODE 2: kv scatter (N=1024, n<512 -> k).
template <int MODE>
__global__ __launch_bounds__(256) void gemm128p3(const u16* __restrict__ A,
                                                 const u16* __restrict__ Bt,
                                                 u16* __restrict__ k_o, u16* __restrict__ v_o,
                                                 float* __restrict__ f_o,
                                                 int K, int nx, int cpx) {
  __shared__ __align__(16) u16 As3[3 * 128 * 32];
  __shared__ __align__(16) u16 Bs3[3 * 128 * 32];
  const int tid = threadIdx.x;
  const int l = tid & 63, w = tid >> 6;
  const int l15 = l & 15, g16 = l >> 4;
  const int wr = w >> 1, wc = w & 1;

  const int oid = blockIdx.x + nx * blockIdx.y;
  const int wid = (oid & 7) * cpx + (oid >> 3);
  const int m0 = (wid / nx) * 128, n0 = (wid % nx) * 128;

  f32x4 acc[4][4] = {};

  const int row0 = tid >> 2, row1 = 64 + (tid >> 2), cc = tid & 3;
  const int sc0 = cc ^ ((row0 >> 1) & 3), sc1 = cc ^ ((row1 >> 1) & 3);
  const u16* pA0 = A + (size_t)(m0 + row0) * K + sc0 * 8;
  const u16* pA1 = A + (size_t)(m0 + row1) * K + sc1 * 8;
  const u16* pB0 = Bt + (size_t)(n0 + row0) * K + sc0 * 8;
  const u16* pB1 = Bt + (size_t)(n0 + row1) * K + sc1 * 8;

#define STAGE(buf)                                                   \
  {                                                                  \
    char* ab = (char*)As3 + (buf) * 8192 + w * 1024;                 \
    char* bb = (char*)Bs3 + (buf) * 8192 + w * 1024;                 \
    gload16(pA0, ab);                                                \
    gload16(pA1, ab + 4096);                                         \
    gload16(pB0, bb);                                                \
    gload16(pB1, bb + 4096);                                         \
    pA0 += 32; pA1 += 32; pB0 += 32; pB1 += 32;                      \
  }

#define COMPUTE(buf)                                                 \
  {                                                                  \
    const u16* AsB = As3 + (buf) * 4096;                             \
    const u16* BsB = Bs3 + (buf) * 4096;                             \
    bf16x8 af[4], bfr[4];                                            \
    _Pragma("unroll")                                                \
    for (int mt = 0; mt < 4; ++mt) {                                 \
      int arow = wr * 64 + mt * 16 + l15;                            \
      af[mt] = *(const bf16x8*)&AsB[arow * 32 +                      \
                                    ((g16 ^ ((arow >> 1) & 3)) * 8)];\
    }                                                                \
    _Pragma("unroll")                                                \
    for (int nt = 0; nt < 4; ++nt) {                                 \
      int brow = wc * 64 + nt * 16 + l15;                            \
      bfr[nt] = *(const bf16x8*)&BsB[brow * 32 +                     \
                                     ((g16 ^ ((brow >> 1) & 3)) * 8)];\
    }                                                                \
    __builtin_amdgcn_s_setprio(1);                                   \
    _Pragma("unroll")                                                \
    for (int mt = 0; mt < 4; ++mt)                                   \
      _Pragma("unroll")                                              \
      for (int nt = 0; nt < 4; ++nt)                                 \
        acc[mt][nt] = mfma16(af[mt], bfr[nt], acc[mt][nt]);          \
    __builtin_amdgcn_s_setprio(0);                                   \
  }

  const int ntiles = K >> 5;
  STAGE(0);
  STAGE(1);
  asm volatile("s_waitcnt vmcnt(4)" ::: "memory");
  __builtin_amdgcn_s_barrier();

  int cur = 0, nxt = 2;
  for (int t = 0; t < ntiles; ++t) {
    const bool more2 = (t + 2 < ntiles);
    if (more2) STAGE(nxt);
    COMPUTE(cur);
    if (t + 1 < ntiles) {
      if (more2) {
        asm volatile("s_waitcnt vmcnt(4)" ::: "memory");
      } else {
        asm volatile("s_waitcnt vmcnt(0)" ::: "memory");
      }
      __builtin_amdgcn_s_barrier();
    }
    cur = (cur == 2) ? 0 : cur + 1;
    nxt = (nxt == 2) ? 0 : nxt + 1;
  }
#undef STAGE
#undef COMPUTE

#pragma unroll
  for (int mt = 0; mt < 4; ++mt) {
#pragma unroll
    for (int r = 0; r < 4; ++r) {
      int row = m0 + wr * 64 + mt * 16 + g16 * 4 + r;
#pragma unroll
      for (int nt = 0; nt < 4; ++nt) {
        int n = n0 + wc * 64 + nt * 16 + l15;
        float val = acc[mt][nt][r];
        if (MODE == 1) {
          f_o[(size_t)row * 2048 + n] = val;
        } else {  // MODE 2: kv scatter, n in [0,1024)
          int b = row >> 11, t = row & (T_SEQ - 1);
          u16 bv = f2bf(val);
          if (n < 512) {
            int h = n >> 7, d = n & 127;
            k_o[((size_t)(b * NKV + h) * T_SEQ + t) * HDIM + d] = bv;
          } else {
            int n2 = n - 512; int h = n2 >> 7, d = n2 & 127;
            v_o[((size_t)(b * NKV + h) * T_SEQ + t) * HDIM + d] = bv;
          }
        }
      }
    }
  }
}

// ---- 256x256 bf16 GEMM: 512 thr (8 waves 2x4), per-wave 128x64, BK=64 ----
// Grid MUST be exactly 256 blocks (1 round, 1 block/CU). MODE 0: q scatter
// (N=2048). MODE 1: fp32 C.
template <int MODE>
__global__ __launch_bounds__(512, 2) void gemm256(const u16* __restrict__ A,
                                                  const u16* __restrict__ Bt,
                                                  u16* __restrict__ q_o,
                                                  float* __restrict__ f_o,
                                                  int K, int ntn, int cpx) {
  __shared__ __align__(16) u16 As[2][256 * 64];
  __shared__ __align__(16) u16 Bs[2][256 * 64];
  const int tid = threadIdx.x;
  const int l = tid & 63, w = tid >> 6;
  const int l16 = l & 15, g16 = l >> 4;
  const int wr = w >> 2, wc = w & 3;

  const int oid = blockIdx.x;
  const int wid = (oid & 7) * cpx + (oid >> 3);
  const int m0 = (wid / ntn) * 256, n0 = (wid % ntn) * 256;

  f32x4 acc[8][4] = {};

  const int srow = tid >> 3, scc = tid & 7;
  const u16* pA[4];
  const u16* pB[4];
#pragma unroll
  for (int j = 0; j < 4; ++j) {
    int row = j * 64 + srow;
    int cc = scc ^ (row & 7);
    pA[j] = A + (size_t)(m0 + row) * K + cc * 8;
    pB[j] = Bt + (size_t)(n0 + row) * K + cc * 8;
  }

#define STAGE(buf)                                              \
  {                                                             \
    char* ab = (char*)As[buf] + w * 1024;                       \
    char* bb = (char*)Bs[buf] + w * 1024;                       \
    _Pragma("unroll")                                           \
    for (int j = 0; j < 4; ++j) {                               \
      gload16(pA[j], ab + j * 8192);                            \
      pA[j] += 64;                                              \
    }                                                           \
    _Pragma("unroll")                                           \
    for (int j = 0; j < 4; ++j) {                               \
      gload16(pB[j], bb + j * 8192);                            \
      pB[j] += 64;                                              \
    }                                                           \
  }

  const int ntk = K >> 6;
  STAGE(0);
  __syncthreads();

  for (int t = 0; t < ntk; ++t) {
    const int buf = t & 1;
    if (t + 1 < ntk) STAGE(buf ^ 1);
#pragma unroll
    for (int ks = 0; ks < 2; ++ks) {
      bf16x8 bfr[4];
#pragma unroll
      for (int nf = 0; nf < 4; ++nf) {
        int brow = wc * 64 + nf * 16 + l16;
        int slot = (ks * 4 + g16) ^ (brow & 7);
        bfr[nf] = *(const bf16x8*)&Bs[buf][brow * 64 + slot * 8];
      }
#pragma unroll
      for (int rh = 0; rh < 2; ++rh) {
        bf16x8 af[4];
#pragma unroll
        for (int f = 0; f < 4; ++f) {
          int arow = wr * 128 + rh * 64 + f * 16 + l16;
          int slot = (ks * 4 + g16) ^ (arow & 7);
          af[f] = *(const bf16x8*)&As[buf][arow * 64 + slot * 8];
        }
        __builtin_amdgcn_s_setprio(1);
#pragma unroll
        for (int f = 0; f < 4; ++f)
#pragma unroll
          for (int nf = 0; nf < 4; ++nf)
            acc[rh * 4 + f][nf] = mfma16(af[f], bfr[nf], acc[rh * 4 + f][nf]);
        __builtin_amdgcn_s_setprio(0);
      }
    }
    __syncthreads();
  }
#undef STAGE

#pragma unroll
  for (int rf = 0; rf < 8; ++rf) {
#pragma unroll
    for (int rr = 0; rr < 4; ++rr) {
      int row = m0 + wr * 128 + rf * 16 + g16 * 4 + rr;
#pragma unroll
      for (int nf = 0; nf < 4; ++nf) {
        int n = n0 + wc * 64 + nf * 16 + l16;
        float val = acc[rf][nf][rr];
        if (MODE == 1) {
          f_o[(size_t)row * 2048 + n] = val;
        } else {  // MODE 0: q scatter (n < 2048 always)
          int b = row >> 11, t = row & (T_SEQ - 1);
          int h = n >> 7, d = n & 127;
          q_o[((size_t)(b * NH + h) * T_SEQ + t) * HDIM + d] = f2bf(val);
        }
      }
    }
  }
}

// ------ merged post-processing: q-rmsrope | k-rmsrope | vtrans (1 launch) ------
// blocks [0,32768): q rows x4; [32768,40960): k rows x4; [40960,41984): vtrans.
__global__ __launch_bounds__(256) void postproc(u16* __restrict__ qbuf,
                                                u16* __restrict__ kbuf,
                                                const u16* __restrict__ vbuf,
                                                u16* __restrict__ vtbuf,
                                                const float* __restrict__ gains) {
  const int bid = blockIdx.x;
  if (bid < 40960) {
    const bool isq = (bid < 32768);
    u16* buf = isq ? qbuf : kbuf;
    const int base = isq ? bid : (bid - 32768);
    const int w = threadIdx.x >> 6, l = threadIdx.x & 63;
    const int rid = base * 4 + w;
    const int t = rid & (T_SEQ - 1);
    const int h = (rid >> 11) % (isq ? NH : NKV);
    u16* p = buf + (size_t)rid * HDIM;
    float x1 = bf2f(p[l]), x2 = bf2f(p[l + 64]);
    float ss = x1 * x1 + x2 * x2;
#pragma unroll
    for (int m = 32; m; m >>= 1) ss += __shfl_xor(ss, m, 64);
    float rn = rsqrtf(ss * (1.0f / 128.0f) + 1.1920928955078125e-7f);
    float g = isq ? gains[h] * (1.4426950408889634f / 11.313708498984761f) : 1.0f;
    float sc = rn * g;
    float inv = exp2f(-(float)l * (13.287712379549449f / 64.0f));
    float ang = (float)t * inv;
    float s, c;
    __sincosf(ang, &s, &c);
    float o1 = (x1 * c + x2 * s) * sc;
    float o2 = (x2 * c - x1 * s) * sc;
    p[l] = f2bf(o1);
    p[l + 64] = f2bf(o2);
  } else {
    __shared__ u16 tileT[64][PSTR];
    const int tidx = bid - 40960;
    const int t0 = (tidx & 31) * 64, d0 = ((tidx >> 5) & 1) * 64, bg = tidx >> 6;
    const int tid = threadIdx.x;
    const int row = tid >> 2, c0 = (tid & 3) * 16;
    const u16* src = vbuf + ((size_t)bg * T_SEQ + t0 + row) * HDIM + d0 + c0;
    u16x8 a = *(const u16x8*)src;
    u16x8 bb = *(const u16x8*)(src + 8);
#pragma unroll
    for (int j = 0; j < 8; ++j) {
      tileT[c0 + j][row] = a[j];
      tileT[c0 + 8 + j][row] = bb[j];
    }
    __syncthreads();
    u16* dst = vtbuf + ((size_t)bg * HDIM + d0 + row) * T_SEQ + t0 + c0;
    *(u16x8*)dst = *(const u16x8*)&tileT[row][c0];
    *(u16x8*)(dst + 8) = *(const u16x8*)&tileT[row][c0 + 8];
  }
}

// ------- flash GQA causal attention v10: 512 threads, 8 waves x 16 q-rows -----
// Ps XOR-swizzled [16][64] (byte ^ (l16&7)<<4, both sides).
// Single-buffer K/V, persistent pointers, wave-uniform diag, den via mfma.
__global__ __launch_bounds__(512) void attn_fwd10(const u16* __restrict__ qb,
                                                  const u16* __restrict__ kb,
                                                  const u16* __restrict__ vtb,
                                                  u16* __restrict__ yb,
                                                  const float* __restrict__ gains) {
  __shared__ __align__(16) u16 Ks[64 * 128];    // [key][d], chunk XOR (row&7)
  __shared__ __align__(16) u16 Vs[128 * 64];    // [d][key], chunk XOR (row&7)
  __shared__ __align__(16) u16 Ps[8][16 * 64];  // per-wave P, XOR-swizzled

  const int tid = threadIdx.x, l = tid & 63, w = tid >> 6;  // w: 0..7
  const int l16 = l & 15, g16 = l >> 4;
  const int pswz = (l16 & 7) * 8;   // u16-index XOR for Ps (== byte<<4)

  const int oid = blockIdx.x + 8 * blockIdx.y;
  const int wid = (oid & 7) * 64 + (oid >> 3);
  const int pair = wid & 7, bh = wid >> 3;
  const int b = bh >> 4, h = bh & 15, gr = h >> 2;

  const float Mh = 16.33f * fabsf(gains[h]) + 0.5f;
  const u16* kbase = kb + (size_t)(b * NKV + gr) * T_SEQ * HDIM;
  const u16* vtbase = vtb + (size_t)(b * NKV + gr) * HDIM * T_SEQ;

  bf16x8 ones;
#pragma unroll
  for (int j = 0; j < 8; ++j) ones[j] = (__bf16)1.0f;

  // persistent staging source pointers (computed once; advance per tile)
  const int krow0 = tid >> 4, kc0 = tid & 15;
  const int krow1 = 32 + (tid >> 4);
  const u16* kp0_base = kbase + (size_t)krow0 * HDIM + (kc0 ^ (krow0 & 7)) * 8;
  const u16* kp1_base = kbase + (size_t)krow1 * HDIM + (kc0 ^ (krow1 & 7)) * 8;
  const int vrow0 = tid >> 3, vc0 = tid & 7;
  const int vrow1 = 64 + (tid >> 3);
  const u16* vp0_base = vtbase + (size_t)vrow0 * T_SEQ + (vc0 ^ (vrow0 & 7)) * 8;
  const u16* vp1_base = vtbase + (size_t)vrow1 * T_SEQ + (vc0 ^ (vrow1 & 7)) * 8;
  char* kd0 = (char*)Ks + (w * 64) * 16;
  char* kd1 = (char*)Ks + (512 + w * 64) * 16;
  char* vd0 = (char*)Vs + (w * 64) * 16;
  char* vd1 = (char*)Vs + (512 + w * 64) * 16;

  for (int phase = 0; phase < 2; ++phase) {
    const int qt = phase ? (15 - pair) : pair;
    const int q0 = qt * 128 + w * 16;   // wave's 16 q-rows
    const int qhi = q0 + 15;

    bf16x8 qf[4];
    const u16* qbase = qb + ((size_t)bh * T_SEQ + q0) * HDIM;
#pragma unroll
    for (int s = 0; s < 4; ++s)
      qf[s] = *(const bf16x8*)(qbase + (size_t)l16 * HDIM + s * 32 + g16 * 8);

    f32x4 oacc[8] = {};
    f32x4 dden = {};
    const int ntile = 2 * qt + 2;

    const u16* kp0 = kp0_base;
    const u16* kp1 = kp1_base;
    const u16* vp0 = vp0_base;
    const u16* vp1 = vp1_base;

    for (int kt = 0; kt < ntile; ++kt) {
      gload16(kp0, kd0);
      gload16(kp1, kd1);
      gload16(vp0, vd0);
      gload16(vp1, vd1);
      kp0 += 64 * HDIM; kp1 += 64 * HDIM;
      vp0 += 64; vp1 += 64;
      __syncthreads();

      if (kt * 64 <= qhi) {
        f32x4 sacc[4] = {};
        __builtin_amdgcn_s_setprio(1);
#pragma unroll
        for (int mt = 0; mt < 4; ++mt) {
          int key = mt * 16 + l16;
#pragma unroll
          for (int s = 0; s < 4; ++s) {
            bf16x8 kf = *(const bf16x8*)&Ks[key * 128 + ((s * 4 + g16) ^ (key & 7)) * 8];
            sacc[mt] = mfma16(kf, qf[s], sacc[mt]);
          }
        }
        __builtin_amdgcn_s_setprio(0);

        if (kt * 64 + 63 > q0) {
          // diagonal-crossing tile: per-element mask
#pragma unroll
          for (int mt = 0; mt < 4; ++mt) {
            int keyb = kt * 64 + mt * 16 + g16 * 4;
            u16x4 p4;
#pragma unroll
            for (int r = 0; r < 4; ++r) {
              float pv = exp2f(sacc[mt][r] - Mh);
              if (keyb + r > q0 + l16) pv = 0.f;
              p4[r] = f2bf(pv);
            }
            *(u16x4*)&Ps[w][l16 * 64 + ((mt * 16 + g16 * 4) ^ pswz)] = p4;
          }
        } else {
          // interior tile: no masking VALU
#pragma unroll
          for (int mt = 0; mt < 4; ++mt) {
            u16x4 p4;
#pragma unroll
            for (int r = 0; r < 4; ++r)
              p4[r] = f2bf(exp2f(sacc[mt][r] - Mh));
            *(u16x4*)&Ps[w][l16 * 64 + ((mt * 16 + g16 * 4) ^ pswz)] = p4;
          }
        }

        __builtin_amdgcn_s_setprio(1);
#pragma unroll
        for (int ks = 0; ks < 2; ++ks) {
          bf16x8 pa = *(const bf16x8*)&Ps[w][l16 * 64 + ((ks * 32 + g16 * 8) ^ pswz)];
          dden = mfma16(pa, ones, dden);
#pragma unroll
          for (int dt = 0; dt < 8; ++dt) {
            int d = dt * 16 + l16;
            bf16x8 vv = *(const bf16x8*)&Vs[d * 64 + (((ks * 4 + g16) ^ (d & 7)) * 8)];
            oacc[dt] = mfma16(pa, vv, oacc[dt]);
          }
        }
        __builtin_amdgcn_s_setprio(0);
      }
      __syncthreads();
    }

    float rden[4];
#pragma unroll
    for (int r = 0; r < 4; ++r) rden[r] = 1.f / dden[r];

#pragma unroll
    for (int dt = 0; dt < 8; ++dt)
#pragma unroll
      for (int r = 0; r < 4; ++r) {
        int t = q0 + g16 * 4 + r;
        int d = dt * 16 + l16;
        yb[(((size_t)b * T_SEQ + t) * NH + h) * HDIM + d] = f2bf(oacc[dt][r] * rden[r]);
      }
    __syncthreads();  // LDS reuse safety before next phase
  }
}

extern "C" void kernel_launch(void* const* d_in, const int* in_sizes, int n_in,
                              void* d_out, int out_size, void* d_ws, size_t ws_size,
                              hipStream_t stream) {
  const float* x = (const float*)d_in[0];
  const float* Wq = (const float*)d_in[1];
  const float* Wk = (const float*)d_in[2];
  const float* Wv = (const float*)d_in[3];
  const float* Wproj = (const float*)d_in[4];
  const float* qg = (const float*)d_in[5];
  float* out = (float*)d_out;

  u16* xbf = (u16*)d_ws;                                   // 8192*2048
  u16* Wqkv = xbf + (size_t)8192 * 2048;                   // 3072*2048 (dead after gemms)
  u16* Wpj = Wqkv + (size_t)3072 * 2048;                   // 2048*2048
  u16* qbuf = Wpj + (size_t)2048 * 2048;                   // 8192*2048
  u16* kbuf = qbuf + (size_t)8192 * 2048;                  // 2048*2048
  u16* vbuf = kbuf + (size_t)2048 * 2048;                  // 2048*2048
  u16* ybuf = xbf;        // alias: x dead after gemms
  u16* vtbuf = Wqkv;      // alias: Wqkv dead after gemms

  cvt_all<<<2048, 256, 0, stream>>>(x, Wq, Wk, Wv, Wproj,
                                    xbf, Wqkv, Wqkv + (size_t)2048 * 2048,
                                    Wqkv + (size_t)2560 * 2048, Wpj);

  // q projection: M=8192 N=2048 -> 32x8 = 256 blocks = exactly 1 round
  gemm256<0><<<256, 512, 0, stream>>>(xbf, Wqkv, qbuf, nullptr, 2048, 8, 32);

  // k+v projection: M=8192 N=1024 -> 8x64 = 512 blocks, 2/CU co-resident
  gemm128p3<2><<<dim3(8, 64), 256, 0, stream>>>(xbf, Wqkv + (size_t)2048 * 2048,
                                                kbuf, vbuf, nullptr, 2048, 8, 64);

  // merged q-rmsrope + k-rmsrope + vtrans (1 launch, 41984 blocks)
  postproc<<<41984, 256, 0, stream>>>(qbuf, kbuf, vbuf, vtbuf, qg);

  attn_fwd10<<<dim3(8, 64), 512, 0, stream>>>(qbuf, kbuf, vtbuf, ybuf, qg);

  gemm256<1><<<256, 512, 0, stream>>>(ybuf, Wpj, nullptr, out, 2048, 8, 32);
}